// Round 8
// baseline (215.048 us; speedup 1.0000x reference)
//
#include <hip/hip_runtime.h>

typedef __bf16 bf16x8 __attribute__((ext_vector_type(8)));
typedef float f32x4 __attribute__((ext_vector_type(4)));

// workspace layout (bytes):
//   Kt : [125][288][32] bf16 (pre-swizzled within each 18432-B slice) at offset 0
//   xb : [2][36][36][36][32] bf16 at offset 2,304,000
#define KT_BYTES 2304000
#define NS 18432   // one B slice (288*32*2 B)
#define NVT 85     // 81 active voxels + 4 zero dummies (v=0 slice is exactly zero)

__device__ __forceinline__ unsigned short f2bf(float f) {
    unsigned int u = __builtin_bit_cast(unsigned int, f);
    unsigned int r = (u + 0x7fffu + ((u >> 16) & 1u)) >> 16;
    return (unsigned short)r;
}

__device__ __forceinline__ float sus(float x) {
    return x > 0.0f ? expf(-1.0f / x) : 0.0f;
}

// ---- active-voxel table (81 voxels with r^2 <= 6) + dummy pad ----
struct VoxTab { int kt[NVT]; int xb[NVT]; };
constexpr VoxTab mk_tab() {
    VoxTab t{};
    int n = 0;
    for (int dx = 0; dx < 5; dx++)
        for (int dy = 0; dy < 5; dy++)
            for (int dz = 0; dz < 5; dz++) {
                int a = dx - 2, b = dy - 2, c = dz - 2;
                if (a * a + b * b + c * c <= 6) {
                    t.kt[n] = (dx * 25 + dy * 5 + dz) * NS;      // byte offset into Kt
                    t.xb[n] = ((dx * 36 + dy) * 36 + dz) * 32;   // short offset into xb
                    n++;
                }
            }
    for (; n < NVT; n++) { t.kt[n] = 0; t.xb[n] = 0; }
    return t;
}
__constant__ VoxTab TAB = mk_tab();

// ---- build conv kernel Kt[v][o][ci] (bf16, PRE-SWIZZLED) ----
__global__ __launch_bounds__(512) void build_kt(const float* __restrict__ w0,
                                                const float* __restrict__ w1,
                                                const float* __restrict__ w2,
                                                const float* __restrict__ wlin,
                                                unsigned short* __restrict__ kt) {
    __shared__ float lw[24576];   // [3][8][32][32] floats = 96 KB
    const int tid = threadIdx.x;
    {
        const float4* s0 = (const float4*)w0;
        const float4* s1 = (const float4*)w1;
        const float4* s2 = (const float4*)w2;
        for (int u = tid; u < 6144; u += 512) {
            int wsel = u >> 11, r = u & 2047;
            float4 v = (wsel == 0 ? s0[r] : (wsel == 1 ? s1[r] : s2[r]));
            ((float4*)lw)[u] = v;
        }
    }
    __syncthreads();

    const int v = blockIdx.x;
    const int dx = v / 25, dy = (v / 5) % 5, dz = v % 5;
    const float lx = (float)(dx - 2), ly = (float)(dy - 2), lz = (float)(dz - 2);
    const float nr = sqrtf(lx * lx + ly * ly + lz * lz);

    float emb[8];
    const float tt = nr * (9.0f / 2.5f);
    const float C = 1.14136f * expf(2.0f);
    #pragma unroll
    for (int j = 1; j <= 8; j++) {
        float d = tt - (float)j;
        emb[j - 1] = C * sus(d + 1.0f) * sus(1.0f - d);
    }

    float ux = 0.f, uy = 0.f, uz = 0.f;
    if (nr > 0.0f) { ux = lx / nr; uy = ly / nr; uz = lz / nr; }
    float Y[9];
    const float s3 = 1.7320508075688772f, s15 = 3.872983346207417f;
    Y[0] = 1.0f;
    Y[1] = s3 * uy; Y[2] = s3 * uz; Y[3] = s3 * ux;
    Y[4] = s15 * ux * uy;
    Y[5] = s15 * uy * uz;
    Y[6] = 1.1180339887498949f * (2.0f * uz * uz - ux * ux - uy * uy);
    Y[7] = s15 * ux * uz;
    Y[8] = 0.5f * s15 * (ux * ux - uy * uy);

    const float rfan = 0.17677669529663687f;  // 1/sqrt(32)

    for (int e = tid; e < 9216; e += 512) {
        const int ci = e / 288, o = e % 288;
        int wsel, co, yi;
        if (o < 32)       { wsel = 0; co = o; yi = 0; }
        else if (o < 128) { int t = o - 32;  wsel = 1; co = t / 3; yi = 1 + t % 3; }
        else              { int t = o - 128; wsel = 2; co = t / 5; yi = 4 + t % 5; }
        const float* w = lw + wsel * 8192;
        float s = 0.0f;
        #pragma unroll
        for (int k = 0; k < 8; k++) s += emb[k] * w[k * 1024 + ci * 32 + co];
        float val = s * (1.0f / 125.0f) * Y[yi] * rfan;
        if (v == 62) val = (o < 32) ? wlin[ci * 32 + o] * rfan : 0.0f;   // center override
        int r = o * 64 + ci * 2;                   // logical byte addr in slice
        int rs = r ^ (((r >> 7) & 7) << 4);        // pre-apply LDS swizzle (involution)
        kt[v * 9216 + (rs >> 1)] = f2bf(val);
    }
}

// ---- pad + convert x to bf16 (16B stores): xb[n][36][36][36][32] ----
__global__ void pad_x2(const float* __restrict__ x, unsigned short* __restrict__ xb) {
    int u = blockIdx.x * blockDim.x + threadIdx.x;   // one 16B unit (8 bf16)
    if (u >= 373248) return;
    const int ci8 = u & 3;
    int t = u >> 2;
    const int pz = t % 36; t /= 36;
    const int py = t % 36; t /= 36;
    const int px = t % 36; const int nn = t / 36;
    const int gx = px - 2, gy = py - 2, gz = pz - 2;
    uint4 ov = {0u, 0u, 0u, 0u};
    if ((unsigned)gx < 32u && (unsigned)gy < 32u && (unsigned)gz < 32u) {
        const float* src = x + ((((size_t)nn * 32 + gx) * 32 + gy) * 32 + gz) * 32 + ci8 * 8;
        float4 f0 = ((const float4*)src)[0];
        float4 f1 = ((const float4*)src)[1];
        ov.x = (unsigned)f2bf(f0.x) | ((unsigned)f2bf(f0.y) << 16);
        ov.y = (unsigned)f2bf(f0.z) | ((unsigned)f2bf(f0.w) << 16);
        ov.z = (unsigned)f2bf(f1.x) | ((unsigned)f2bf(f1.y) << 16);
        ov.w = (unsigned)f2bf(f1.z) | ((unsigned)f2bf(f1.w) << 16);
    }
    ((uint4*)xb)[u] = ov;
}

// ---- conv: implicit GEMM, block = 64 positions x 288 outputs, 6 waves ----
// Wave wv owns M=64 (all positions) x N=48 (o in [wv*48, wv*48+48)).
// acc = 12 frags = 48 AGPR. Each wave stages EXACTLY the 3 KB B sub-slice it
// reads (pre-swizzled Kt, swizzle is wave-local) -> NO cross-wave deps ->
// NO s_barrier in the main loop. Per-wave ring-4 + vmcnt(3), A dbuf in regs.
__global__ __launch_bounds__(384, 3) void conv_mfma(const unsigned short* __restrict__ xb,
                                                    const unsigned short* __restrict__ kt,
                                                    float* __restrict__ out) {
    __shared__ __align__(16) char lds[4 * NS];
    const int tid = threadIdx.x;
    const int lane = tid & 63;
    const int wv = tid >> 6;          // 0..5 -> N-group
    const int l15 = lane & 15, l16 = lane >> 4;
    const int o0 = wv * 48;

    // XCD-bijective swizzle: 1024 blocks = 8 XCDs x 128
    const int b = blockIdx.x;
    const int sw = (b & 7) * 128 + (b >> 3);
    const int nn = sw >> 9;
    const int rem = sw & 511;
    const int X0 = rem >> 4;          // 1 x-plane
    const int Y0 = (rem & 15) * 2;    // 2 y-rows

    const unsigned short* xbase = xb + (size_t)nn * 1492992;

    // A frag s: (y = Y0 + (s>>1), z-half = s&1); row within frag = l15 (z), k = l16*8..
    int aoff[4];
    #pragma unroll
    for (int s = 0; s < 4; s++)
        aoff[s] = ((X0 * 36 + Y0 + (s >> 1)) * 36 + (s & 1) * 16 + l15) * 32 + l16 * 8;

    // B LDS base (bytes, swizzled); frag nt at +nt*1024 (swizzle indep. of nt)
    int bbase = (o0 + l15) * 64 + l16 * 16;
    bbase ^= ((bbase >> 7) & 7) << 4;

    // wave-private stage: 3 KB sub-slice, 3 x 16B-granule gload_lds
    auto stageB = [&](int ktByte, int slot) {
        const char* src = (const char*)kt + ktByte + wv * 3072 + lane * 16;
        char* dst = lds + slot * NS + wv * 3072 + lane * 16;
        __builtin_amdgcn_global_load_lds(
            (const __attribute__((address_space(1))) void*)src,
            (__attribute__((address_space(3))) void*)dst, 16, 0, 0);
        __builtin_amdgcn_global_load_lds(
            (const __attribute__((address_space(1))) void*)(src + 1024),
            (__attribute__((address_space(3))) void*)(dst + 1024), 16, 0, 0);
        __builtin_amdgcn_global_load_lds(
            (const __attribute__((address_space(1))) void*)(src + 2048),
            (__attribute__((address_space(3))) void*)(dst + 2048), 16, 0, 0);
    };

    bf16x8 A0[4], A1[4];
    f32x4 acc[4][3];
    #pragma unroll
    for (int i = 0; i < 4; i++)
        #pragma unroll
        for (int j = 0; j < 3; j++)
            acc[i][j] = (f32x4){0.f, 0.f, 0.f, 0.f};

    auto loadA = [&](bf16x8* A, int xoff) {
        #pragma unroll
        for (int s = 0; s < 4; s++)
            A[s] = *(const bf16x8*)(xbase + aoff[s] + xoff);
    };

    auto compute = [&](bf16x8* A, int slot) {
        const char* bp = lds + slot * NS + bbase;
        #pragma unroll
        for (int nt = 0; nt < 3; nt++) {
            bf16x8 B = *(const bf16x8*)(bp + nt * 1024);
            #pragma unroll
            for (int s = 0; s < 4; s++)
                acc[s][nt] = __builtin_amdgcn_mfma_f32_16x16x32_bf16(A[s], B, acc[s][nt], 0, 0, 0);
        }
    };

    // PHASE(k): per-wave vmcnt(3) [drains A(k) + B(k); leaves stage(k+2) in flight];
    // loadA(k+1) BEFORE stage(k+3) so next phase's vmcnt(3) drains A first.
    #define PHASE(CUR, NXT, K)                                          \
        asm volatile("s_waitcnt vmcnt(3)" ::: "memory");                \
        __builtin_amdgcn_sched_barrier(0);                              \
        loadA(NXT, TAB.xb[(K) + 1]);                                    \
        stageB(TAB.kt[(K) + 3], ((K) + 3) & 3);                         \
        compute(CUR, (K) & 3);

    // prologue: A(0) first (so phase-0 vmcnt(3) drains it), then slots 0,1,2
    loadA(A0, TAB.xb[0]);
    stageB(TAB.kt[0], 0);
    stageB(TAB.kt[1], 1);
    stageB(TAB.kt[2], 2);

    #pragma unroll 1
    for (int g = 0; g < 41; g++) {
        const int k = 2 * g;
        PHASE(A0, A1, k + 0)
        PHASE(A1, A0, k + 1)
    }
    #undef PHASE

    // ---- epilogue: D row = 4*l16 + r (within frag), col = l15 (n) ----
    #pragma unroll
    for (int s = 0; s < 4; s++) {
        const int y = Y0 + (s >> 1);
        #pragma unroll
        for (int r = 0; r < 4; r++) {
            int z = (s & 1) * 16 + l16 * 4 + r;
            size_t base = ((((size_t)nn * 32 + X0) * 32 + y) * 32 + z) * 288 + o0 + l15;
            #pragma unroll
            for (int nt = 0; nt < 3; nt++)
                out[base + nt * 16] = acc[s][nt][r];
        }
    }
}

extern "C" void kernel_launch(void* const* d_in, const int* in_sizes, int n_in,
                              void* d_out, int out_size, void* d_ws, size_t ws_size,
                              hipStream_t stream) {
    const float* x    = (const float*)d_in[0];
    const float* w0   = (const float*)d_in[1];
    const float* w1   = (const float*)d_in[2];
    const float* w2   = (const float*)d_in[3];
    const float* wlin = (const float*)d_in[4];
    unsigned short* kt = (unsigned short*)d_ws;
    unsigned short* xb = (unsigned short*)((char*)d_ws + KT_BYTES);
    float* out = (float*)d_out;

    hipLaunchKernelGGL(build_kt, dim3(125), dim3(512), 0, stream, w0, w1, w2, wlin, kt);
    hipLaunchKernelGGL(pad_x2, dim3(1458), dim3(256), 0, stream, x, xb);
    hipLaunchKernelGGL(conv_mfma, dim3(1024), dim3(384), 0, stream, xb, kt, out);
}

// Round 9
// 149.154 us; speedup vs baseline: 1.4418x; 1.4418x over previous
//
#include <hip/hip_runtime.h>

typedef __bf16 bf16x8 __attribute__((ext_vector_type(8)));
typedef float f32x16 __attribute__((ext_vector_type(16)));

// workspace layout (bytes):
//   Kt : [125] slices, each 18432 B, FRAGMENT-MAJOR for 32x32x16 MFMA:
//        elem (o,ci) at e = ((ng*2+kh)*64 + hi*32 + ol)*8 + j  (shorts)
//        where ng=o>>5, ol=o&31, kh=ci>>4, hi=(ci>>3)&1, j=ci&7
//   xb : [2][2kh][36][36][36][16] bf16 at offset 2,304,000 (5,971,968 B)
#define KT_BYTES 2304000
#define NS 18432          // one B slice
#define KHS 746496        // kh stride in xb (shorts) = 36*36*36*16
#define NVT 88            // 81 active + 7 zero dummies (v=0 slice is exactly zero)

__device__ __forceinline__ unsigned short f2bf(float f) {
    unsigned int u = __builtin_bit_cast(unsigned int, f);
    unsigned int r = (u + 0x7fffu + ((u >> 16) & 1u)) >> 16;
    return (unsigned short)r;
}

__device__ __forceinline__ float sus(float x) {
    return x > 0.0f ? expf(-1.0f / x) : 0.0f;
}

// ---- active-voxel table (81 voxels with r^2 <= 6) + dummy pad ----
struct VoxTab { int kt[NVT]; int xb[NVT]; };
constexpr VoxTab mk_tab() {
    VoxTab t{};
    int n = 0;
    for (int dx = 0; dx < 5; dx++)
        for (int dy = 0; dy < 5; dy++)
            for (int dz = 0; dz < 5; dz++) {
                int a = dx - 2, b = dy - 2, c = dz - 2;
                if (a * a + b * b + c * c <= 6) {
                    t.kt[n] = (dx * 25 + dy * 5 + dz) * NS;          // byte offset into Kt
                    t.xb[n] = ((dx * 36 + dy) * 36 + dz) * 16;       // short offset into xb (16/pos)
                    n++;
                }
            }
    for (; n < NVT; n++) { t.kt[n] = 0; t.xb[n] = 0; }
    return t;
}
__constant__ VoxTab TAB = mk_tab();

// ---- build conv kernel Kt (bf16, fragment-major) ----
__global__ __launch_bounds__(512) void build_kt(const float* __restrict__ w0,
                                                const float* __restrict__ w1,
                                                const float* __restrict__ w2,
                                                const float* __restrict__ wlin,
                                                unsigned short* __restrict__ kt) {
    __shared__ float lw[24576];   // [3][8][32][32] floats = 96 KB
    const int tid = threadIdx.x;
    {
        const float4* s0 = (const float4*)w0;
        const float4* s1 = (const float4*)w1;
        const float4* s2 = (const float4*)w2;
        for (int u = tid; u < 6144; u += 512) {
            int wsel = u >> 11, r = u & 2047;
            float4 v = (wsel == 0 ? s0[r] : (wsel == 1 ? s1[r] : s2[r]));
            ((float4*)lw)[u] = v;
        }
    }
    __syncthreads();

    const int v = blockIdx.x;
    const int dx = v / 25, dy = (v / 5) % 5, dz = v % 5;
    const float lx = (float)(dx - 2), ly = (float)(dy - 2), lz = (float)(dz - 2);
    const float nr = sqrtf(lx * lx + ly * ly + lz * lz);

    float emb[8];
    const float tt = nr * (9.0f / 2.5f);
    const float C = 1.14136f * expf(2.0f);
    #pragma unroll
    for (int j = 1; j <= 8; j++) {
        float d = tt - (float)j;
        emb[j - 1] = C * sus(d + 1.0f) * sus(1.0f - d);
    }

    float ux = 0.f, uy = 0.f, uz = 0.f;
    if (nr > 0.0f) { ux = lx / nr; uy = ly / nr; uz = lz / nr; }
    float Y[9];
    const float s3 = 1.7320508075688772f, s15 = 3.872983346207417f;
    Y[0] = 1.0f;
    Y[1] = s3 * uy; Y[2] = s3 * uz; Y[3] = s3 * ux;
    Y[4] = s15 * ux * uy;
    Y[5] = s15 * uy * uz;
    Y[6] = 1.1180339887498949f * (2.0f * uz * uz - ux * ux - uy * uy);
    Y[7] = s15 * ux * uz;
    Y[8] = 0.5f * s15 * (ux * ux - uy * uy);

    const float rfan = 0.17677669529663687f;  // 1/sqrt(32)

    for (int e = tid; e < 9216; e += 512) {
        const int ci = e / 288, o = e % 288;   // proven-fast LDS read pattern
        int wsel, co, yi;
        if (o < 32)       { wsel = 0; co = o; yi = 0; }
        else if (o < 128) { int t = o - 32;  wsel = 1; co = t / 3; yi = 1 + t % 3; }
        else              { int t = o - 128; wsel = 2; co = t / 5; yi = 4 + t % 5; }
        const float* w = lw + wsel * 8192;
        float s = 0.0f;
        #pragma unroll
        for (int k = 0; k < 8; k++) s += emb[k] * w[k * 1024 + ci * 32 + co];
        float val = s * (1.0f / 125.0f) * Y[yi] * rfan;
        if (v == 62) val = (o < 32) ? wlin[ci * 32 + o] * rfan : 0.0f;   // center override
        // fragment-major store index
        const int ng = o >> 5, ol = o & 31, kh = ci >> 4, hi = (ci >> 3) & 1, j = ci & 7;
        const int e2 = (((((ng << 1) | kh) << 6) | (hi << 5) | ol) << 3) | j;
        kt[v * 9216 + e2] = f2bf(val);
    }
}

// ---- pad + convert x to bf16, kh-split: xb[n][kh][36][36][36][16] ----
__global__ void pad_x3(const float* __restrict__ x, unsigned short* __restrict__ xb) {
    int u = blockIdx.x * blockDim.x + threadIdx.x;   // one 16B unit (8 bf16)
    if (u >= 373248) return;
    const int j8 = u & 1;
    int t = u >> 1;
    const int pz = t % 36; t /= 36;
    const int py = t % 36; t /= 36;
    const int px = t % 36; t /= 36;
    const int kh = t & 1;  const int nn = t >> 1;
    const int gx = px - 2, gy = py - 2, gz = pz - 2;
    uint4 ov = {0u, 0u, 0u, 0u};
    if ((unsigned)gx < 32u && (unsigned)gy < 32u && (unsigned)gz < 32u) {
        const float* src = x + ((((size_t)nn * 32 + gx) * 32 + gy) * 32 + gz) * 32 + kh * 16 + j8 * 8;
        float4 f0 = ((const float4*)src)[0];
        float4 f1 = ((const float4*)src)[1];
        ov.x = (unsigned)f2bf(f0.x) | ((unsigned)f2bf(f0.y) << 16);
        ov.y = (unsigned)f2bf(f0.z) | ((unsigned)f2bf(f0.w) << 16);
        ov.z = (unsigned)f2bf(f1.x) | ((unsigned)f2bf(f1.y) << 16);
        ov.w = (unsigned)f2bf(f1.z) | ((unsigned)f2bf(f1.w) << 16);
    }
    ((uint4*)xb)[u] = ov;
}

// ---- conv: implicit GEMM, 32x32x16 MFMA, block = 128 pos x 288 outs, 6 waves ----
// Wave (wm,wn): M=64 (2 z-column frags at y=Y0+wm*2+f), N=96 (3 o-groups).
// acc[2][3] f32x16 = 96 AGPR. B: 4-slot LDS ring, fragment-major (linear
// ds_read, 0 conflicts, no swizzle). R7-proven vmcnt(8)+barrier 2-voxel phase.
__global__ __launch_bounds__(384, 3) void conv_mfma(const unsigned short* __restrict__ xb,
                                                    const unsigned short* __restrict__ kt,
                                                    float* __restrict__ out) {
    __shared__ __align__(16) char lds[4 * NS];
    const int tid = threadIdx.x;
    const int lane = tid & 63;
    const int wv = tid >> 6;          // 0..5
    const int wm = wv & 1, wn = wv >> 1;
    const int l31 = lane & 31, lhi = lane >> 5;

    // XCD-bijective swizzle: 512 blocks = 8 XCDs x 64
    const int b = blockIdx.x;
    const int sw = (b & 7) * 64 + (b >> 3);
    const int nn = sw >> 8;
    const int X0 = (sw >> 3) & 31;    // 1 x-plane
    const int Y0 = (sw & 7) * 4;      // 4 y-rows (wm*2 + f)

    const unsigned short* xb_n = xb + (size_t)nn * 2 * KHS;

    // A base (shorts, within a kh-plane): pos=(X0, Y0+wm*2, z=l31), 16 ci/pos
    const int abase = ((X0 * 36 + Y0 + wm * 2) * 36 + l31) * 16 + lhi * 8;

    // B LDS base: lds + slot*NS + wn*6144 + (ngl*2+kh)*1024 + lane*16 (linear!)
    const char* bb = lds + wn * 6144 + lane * 16;

    auto stageB = [&](int ktByte, int slot) {
        const char* src = (const char*)kt + ktByte + wv * 3072 + lane * 16;
        char* dst = lds + slot * NS + wv * 3072;
        __builtin_amdgcn_global_load_lds(
            (const __attribute__((address_space(1))) void*)src,
            (__attribute__((address_space(3))) void*)dst, 16, 0, 0);
        __builtin_amdgcn_global_load_lds(
            (const __attribute__((address_space(1))) void*)(src + 1024),
            (__attribute__((address_space(3))) void*)(dst + 1024), 16, 0, 0);
        __builtin_amdgcn_global_load_lds(
            (const __attribute__((address_space(1))) void*)(src + 2048),
            (__attribute__((address_space(3))) void*)(dst + 2048), 16, 0, 0);
    };

    bf16x8 A0[2][2], A1[2][2];   // [f][kh]
    f32x16 acc[2][3];            // [f][ngl]
    #pragma unroll
    for (int i = 0; i < 2; i++)
        #pragma unroll
        for (int j = 0; j < 3; j++)
            acc[i][j] = (f32x16)(0.0f);

    auto loadA = [&](bf16x8 (&A)[2][2], int xoff) {
        const unsigned short* p0 = xb_n + abase + xoff;          // kh=0 plane
        const unsigned short* p1 = p0 + KHS;                     // kh=1 plane
        A[0][0] = *(const bf16x8*)p0;
        A[1][0] = *(const bf16x8*)(p0 + 576);    // f=1: +36*16 shorts
        A[0][1] = *(const bf16x8*)p1;
        A[1][1] = *(const bf16x8*)(p1 + 576);
    };

    auto compute = [&](bf16x8 (&A)[2][2], int slot) {
        const char* bp = bb + slot * NS;
        #pragma unroll
        for (int ngl = 0; ngl < 3; ngl++) {
            #pragma unroll
            for (int kh = 0; kh < 2; kh++) {
                bf16x8 B = *(const bf16x8*)(bp + (ngl * 2 + kh) * 1024);
                acc[0][ngl] = __builtin_amdgcn_mfma_f32_32x32x16_bf16(A[0][kh], B, acc[0][ngl], 0, 0, 0);
                acc[1][ngl] = __builtin_amdgcn_mfma_f32_32x32x16_bf16(A[1][kh], B, acc[1][ngl], 0, 0, 0);
            }
        }
    };

    // PHASE: vmcnt(8) drains prev stages (6) exactly, keeps A loads (8) in
    // flight (compiler inserts the A-use wait itself); barrier publishes.
    #define PHASE(CUR, NXT, KC, S0, S1, S2, S3)                         \
        asm volatile("s_waitcnt vmcnt(8)" ::: "memory");                \
        __builtin_amdgcn_sched_barrier(0);                              \
        __builtin_amdgcn_s_barrier();                                   \
        __builtin_amdgcn_sched_barrier(0);                              \
        stageB(TAB.kt[(KC) + 2], S2);                                   \
        stageB(TAB.kt[(KC) + 3], S3);                                   \
        __builtin_amdgcn_s_setprio(1);                                  \
        compute(CUR, S0);                                               \
        compute(NXT, S1);                                               \
        __builtin_amdgcn_s_setprio(0);                                  \
        __builtin_amdgcn_sched_barrier(0);                              \
        loadA(CUR, TAB.xb[(KC) + 2]);                                   \
        loadA(NXT, TAB.xb[(KC) + 3]);

    // prologue: slots 0,1 + A(0),A(1)
    stageB(TAB.kt[0], 0);
    stageB(TAB.kt[1], 1);
    loadA(A0, TAB.xb[0]);
    loadA(A1, TAB.xb[1]);

    #pragma unroll 1
    for (int g = 0; g < 21; g++) {
        const int k = 4 * g;
        PHASE(A0, A1, k + 0, 0, 1, 2, 3)
        PHASE(A0, A1, k + 2, 2, 3, 0, 1)
    }
    #undef PHASE

    // ---- epilogue: C/D col = l31 (o), row = (r&3) + 8*(r>>2) + 4*lhi (z) ----
    const size_t obase = (((size_t)nn * 32 + X0) * 32 + Y0 + wm * 2) * 32 * 288;
    #pragma unroll
    for (int f = 0; f < 2; f++) {
        #pragma unroll
        for (int ngl = 0; ngl < 3; ngl++) {
            const int o = wn * 96 + ngl * 32 + l31;
            #pragma unroll
            for (int r = 0; r < 16; r++) {
                const int z = (r & 3) + 8 * (r >> 2) + 4 * lhi;
                out[obase + (size_t)f * (32 * 288) + (size_t)z * 288 + o] = acc[f][ngl][r];
            }
        }
    }
}

extern "C" void kernel_launch(void* const* d_in, const int* in_sizes, int n_in,
                              void* d_out, int out_size, void* d_ws, size_t ws_size,
                              hipStream_t stream) {
    const float* x    = (const float*)d_in[0];
    const float* w0   = (const float*)d_in[1];
    const float* w1   = (const float*)d_in[2];
    const float* w2   = (const float*)d_in[3];
    const float* wlin = (const float*)d_in[4];
    unsigned short* kt = (unsigned short*)d_ws;
    unsigned short* xb = (unsigned short*)((char*)d_ws + KT_BYTES);
    float* out = (float*)d_out;

    hipLaunchKernelGGL(build_kt, dim3(125), dim3(512), 0, stream, w0, w1, w2, wlin, kt);
    hipLaunchKernelGGL(pad_x3, dim3(1458), dim3(256), 0, stream, x, xb);
    hipLaunchKernelGGL(conv_mfma, dim3(512), dim3(384), 0, stream, xb, kt, out);
}